// Round 11
// baseline (108.185 us; speedup 1.0000x reference)
//
#include <hip/hip_runtime.h>
#include <math.h>

#define NB     512
#define NV     6890
#define NF     13776
#define NVHD   20000
#define NPARTS 10
#define NTHREADS 1024
#define NWAVES (NTHREADS/64)
#define CUT    6697                // verts < CUT live in LDS; slot CUT = dummy
#define NCHF   ((NF + 63) / 64)    // 216
#define NCHH   ((NVHD + 63) / 64)  // 313

// ---- Fused precompute: build + overflow-split + per-part HD counts.
//      Deterministic (ballot-rank compaction, no atomics). 2 blocks.
//      counts[0]=nofF, counts[1]=nofH, counts[2+p]=n_p.
__global__ __launch_bounds__(1024) void prep(
    const float* __restrict__ bary,
    const int*   __restrict__ faces,
    const int*   __restrict__ hd_fid,
    const int*   __restrict__ part_fid,
    uint2* __restrict__ f_pack,    // [NF]  clean/neutral
    uint4* __restrict__ hd_pack,   // [NVHD] clean/neutral
    uint2* __restrict__ ovf_f,     // compacted overflow faces
    uint4* __restrict__ ovf_h,     // compacted overflow HD entries
    int*   __restrict__ counts)
{
    __shared__ int cnt[NCHH];          // max(NCHF,NCHH)
    __shared__ int snp[NWAVES][NPARTS];
    const int tid = threadIdx.x, wave = tid >> 6, lane = tid & 63;
    const unsigned long long lowmask = (1ull << lane) - 1ull;

    if (blockIdx.x == 0) {
        // ---------- faces ----------
        for (int c = wave; c < NCHF; c += NWAVES) {
            int i = c * 64 + lane;
            bool bad = false;
            if (i < NF) {
                int i0 = faces[3*i+0], i1 = faces[3*i+1], i2 = faces[3*i+2];
                bad = (i0 >= CUT) || (i1 >= CUT) || (i2 >= CUT);
            }
            unsigned long long m = __ballot(bad);
            if (lane == 0) cnt[c] = (int)__popcll(m);
        }
        __syncthreads();
        if (wave == 0) {
            int carry = 0;
            #pragma unroll
            for (int seg = 0; seg < (NCHF + 63) / 64; seg++) {
                int idx = seg * 64 + lane;
                int v = (idx < NCHF) ? cnt[idx] : 0;
                int incl = v;
                #pragma unroll
                for (int off = 1; off < 64; off <<= 1) { int n = __shfl_up(incl, off, 64); if (lane >= off) incl += n; }
                if (idx < NCHF) cnt[idx] = incl - v + carry;
                carry += __shfl(incl, 63, 64);
            }
            if (lane == 0) counts[0] = carry;
        }
        __syncthreads();
        for (int c = wave; c < NCHF; c += NWAVES) {
            int i = c * 64 + lane;
            bool valid = i < NF;
            uint2 ft = make_uint2(0u, 0u);
            bool bad = false;
            if (valid) {
                int i0 = faces[3*i+0], i1 = faces[3*i+1], i2 = faces[3*i+2];
                ft = make_uint2((unsigned)i0 | ((unsigned)i1 << 16),
                                (unsigned)i2 | ((unsigned)part_fid[i] << 16));
                bad = (i0 >= CUT) || (i1 >= CUT) || (i2 >= CUT);
            }
            unsigned long long m = __ballot(bad);
            if (valid) {
                if (bad) {
                    int rank = (int)__popcll(m & lowmask);
                    ovf_f[cnt[c] + rank] = ft;
                    // degenerate face (all corners = dummy) -> vol = 0 exactly
                    f_pack[i] = make_uint2((unsigned)CUT | ((unsigned)CUT << 16), (unsigned)CUT);
                } else {
                    f_pack[i] = ft;
                }
            }
        }
    } else {
        // ---------- HD entries + n_p histogram ----------
        int np[NPARTS];
        #pragma unroll
        for (int q = 0; q < NPARTS; q++) np[q] = 0;

        for (int c = wave; c < NCHH; c += NWAVES) {
            int i = c * 64 + lane;
            bool bad = false;
            if (i < NVHD) {
                int fid = hd_fid[i];
                int i0 = faces[3*fid+0], i1 = faces[3*fid+1], i2 = faces[3*fid+2];
                int p  = part_fid[fid];
                #pragma unroll
                for (int q = 0; q < NPARTS; q++) np[q] += (p == q) ? 1 : 0;
                bad = (i0 >= CUT) || (i1 >= CUT) || (i2 >= CUT);
            }
            unsigned long long m = __ballot(bad);
            if (lane == 0) cnt[c] = (int)__popcll(m);
        }
        __syncthreads();
        if (wave == 0) {
            int carry = 0;
            #pragma unroll
            for (int seg = 0; seg < (NCHH + 63) / 64; seg++) {
                int idx = seg * 64 + lane;
                int v = (idx < NCHH) ? cnt[idx] : 0;
                int incl = v;
                #pragma unroll
                for (int off = 1; off < 64; off <<= 1) { int n = __shfl_up(incl, off, 64); if (lane >= off) incl += n; }
                if (idx < NCHH) cnt[idx] = incl - v + carry;
                carry += __shfl(incl, 63, 64);
            }
            if (lane == 0) counts[1] = carry;
        }
        __syncthreads();
        for (int c = wave; c < NCHH; c += NWAVES) {
            int i = c * 64 + lane;
            bool valid = i < NVHD;
            uint4 hp = make_uint4(0u, 0u, 0u, 0u);
            bool bad = false;
            if (valid) {
                int fid = hd_fid[i];
                int i0 = faces[3*fid+0], i1 = faces[3*fid+1], i2 = faces[3*fid+2];
                float b0 = bary[3*i+0], b1 = bary[3*i+1], b2 = bary[3*i+2];
                float inv = 1.0f / (b0 + b1 + b2);
                hp = make_uint4((unsigned)i0 | ((unsigned)i1 << 16),
                                (unsigned)i2 | ((unsigned)part_fid[fid] << 16),
                                __float_as_uint(b0*inv), __float_as_uint(b1*inv));
                bad = (i0 >= CUT) || (i1 >= CUT) || (i2 >= CUT);
            }
            unsigned long long m = __ballot(bad);
            if (valid) {
                if (bad) {
                    int rank = (int)__popcll(m & lowmask);
                    ovf_h[cnt[c] + rank] = hp;
                    // dummy corners (y=100 -> pw=0), p=NPARTS -> vol=spart[10]=0
                    hd_pack[i] = make_uint4((unsigned)CUT | ((unsigned)CUT << 16),
                                            (unsigned)CUT | ((unsigned)NPARTS << 16),
                                            0u, 0u);
                } else {
                    hd_pack[i] = hp;
                }
            }
        }
        // reduce n_p: wave shuffle -> LDS -> 10 threads
        #pragma unroll
        for (int q = 0; q < NPARTS; q++) {
            int s = np[q];
            #pragma unroll
            for (int off = 32; off > 0; off >>= 1) s += __shfl_down(s, off, 64);
            np[q] = s;
        }
        if (lane == 0) {
            #pragma unroll
            for (int q = 0; q < NPARTS; q++) snp[wave][q] = np[q];
        }
        __syncthreads();
        if (tid < NPARTS) {
            int s = 0;
            #pragma unroll
            for (int w = 0; w < NWAVES; w++) s += snp[w][tid];
            counts[2 + tid] = s;
        }
    }
}

__global__ __launch_bounds__(NTHREADS, 8) void stab_kernel(
    const float* __restrict__ vertices,   // [B][V][3] f32
    const uint2* __restrict__ f_pack,     // [NF] clean/neutral
    const uint4* __restrict__ hd_pack,    // [NVHD] clean/neutral
    const uint2* __restrict__ ovf_f,
    const uint4* __restrict__ ovf_h,
    const int*   __restrict__ counts,
    float*       __restrict__ out)        // [B]
{
    __shared__ float2 sxy[CUT + 1];            // 53584 B
    __shared__ float  szz[CUT + 1];            // 26792 B
    __shared__ float  spart[NPARTS + 1];       // 44 B  (spart[10] = 0)
    __shared__ float  sredp[NWAVES][NPARTS];   // 640 B  -> ~81060 total (2 blocks/CU)

    const int tid  = threadIdx.x;
    const int b    = blockIdx.x;
    const int wave = tid >> 6;
    const int lane = tid & 63;
    const float* __restrict__ vb = vertices + (size_t)b * (NV * 3);

    // ---- Phase A: stage verts [0,CUT) + dummy slot ----
    for (int v = tid; v < CUT; v += NTHREADS) {
        float x = vb[3 * v + 0];
        float y = vb[3 * v + 1];
        float z = vb[3 * v + 2];
        sxy[v] = make_float2(x, y);
        szz[v] = z;
    }
    if (tid == 0) { sxy[CUT] = make_float2(0.f, 100.f); szz[CUT] = 0.f; }
    __syncthreads();

    // ---- Phase B: clean faces, pure-LDS, branch-free ----
    float accp[NPARTS];
    #pragma unroll
    for (int q = 0; q < NPARTS; q++) accp[q] = 0.f;

    #pragma unroll 2
    for (int f = tid; f < NF; f += NTHREADS) {
        uint2 ft = f_pack[f];
        int i0 = ft.x & 0xFFFF, i1 = ft.x >> 16;
        int i2 = ft.y & 0xFFFF, p  = (int)(ft.y >> 16);
        float2 t0 = sxy[i0]; float z0 = szz[i0];
        float2 t1 = sxy[i1]; float z1 = szz[i1];
        float2 t2 = sxy[i2]; float z2 = szz[i2];
        float cx = t0.y * z1   - z0   * t1.y;
        float cy = z0   * t1.x - t0.x * z1;
        float cz = t0.x * t1.y - t0.y * t1.x;
        float vol = (cx * t2.x + cy * t2.y + cz * z2) * (1.0f / 6.0f);
        #pragma unroll
        for (int q = 0; q < NPARTS; q++) accp[q] += (p == q) ? vol : 0.f;
    }

    // ---- Phase B-ovf: rare entries, global reads (L2-hot) ----
    const int nofF = counts[0];
    for (int k = tid; k < nofF; k += NTHREADS) {
        uint2 ft = ovf_f[k];
        int i0 = ft.x & 0xFFFF, i1 = ft.x >> 16;
        int i2 = ft.y & 0xFFFF, p  = (int)(ft.y >> 16);
        float x0 = vb[3*i0+0], y0 = vb[3*i0+1], z0 = vb[3*i0+2];
        float x1 = vb[3*i1+0], y1 = vb[3*i1+1], z1 = vb[3*i1+2];
        float x2 = vb[3*i2+0], y2 = vb[3*i2+1], z2 = vb[3*i2+2];
        float cx = y0 * z1 - z0 * y1;
        float cy = z0 * x1 - x0 * z1;
        float cz = x0 * y1 - y0 * x1;
        float vol = (cx * x2 + cy * y2 + cz * z2) * (1.0f / 6.0f);
        #pragma unroll
        for (int q = 0; q < NPARTS; q++) accp[q] += (p == q) ? vol : 0.f;
    }

    #pragma unroll
    for (int q = 0; q < NPARTS; q++) {
        float s = accp[q];
        #pragma unroll
        for (int off = 32; off > 0; off >>= 1) s += __shfl_down(s, off, 64);
        accp[q] = s;
    }
    if (lane == 0) {
        #pragma unroll
        for (int q = 0; q < NPARTS; q++) sredp[wave][q] = accp[q];
    }
    __syncthreads();
    if (tid < NPARTS) {
        float s = 0.f;
        #pragma unroll
        for (int w = 0; w < NWAVES; w++) s += sredp[w][tid];
        spart[tid] = s;
    }
    if (tid == NPARTS) spart[NPARTS] = 0.f;
    __syncthreads();

    // ---- Phase C: clean HD entries (sVol dropped -> computed from n_p) ----
    float sVx = 0.f, sVz = 0.f;
    float sPx = 0.f, sPz = 0.f, sPw = 0.f;

    #pragma unroll 2
    for (int v = tid; v < NVHD; v += NTHREADS) {
        uint4 hp = hd_pack[v];
        int i0 = hp.x & 0xFFFF, i1 = hp.x >> 16;
        int i2 = hp.y & 0xFFFF, p  = (int)(hp.y >> 16);
        float w0 = __uint_as_float(hp.z);
        float w1 = __uint_as_float(hp.w);
        float w2 = 1.0f - w0 - w1;
        float2 t0 = sxy[i0]; float z0 = szz[i0];
        float2 t1 = sxy[i1]; float z1 = szz[i1];
        float2 t2 = sxy[i2]; float z2 = szz[i2];
        float x = w0 * t0.x + w1 * t1.x + w2 * t2.x;
        float y = w0 * t0.y + w1 * t1.y + w2 * t2.y;
        float z = w0 * z0   + w1 * z1   + w2 * z2;
        float vol = spart[p];
        float pw  = (y < 0.f) ? fmaf(-100.f, y, 1.f) : __expf(-10.f * y);
        sVx += x * vol;  sVz += z * vol;
        sPx += x * pw;   sPz += z * pw;   sPw += pw;
    }

    // ---- Phase C-ovf ----
    const int nofH = counts[1];
    for (int k = tid; k < nofH; k += NTHREADS) {
        uint4 hp = ovf_h[k];
        int i0 = hp.x & 0xFFFF, i1 = hp.x >> 16;
        int i2 = hp.y & 0xFFFF, p  = (int)(hp.y >> 16);
        float w0 = __uint_as_float(hp.z);
        float w1 = __uint_as_float(hp.w);
        float w2 = 1.0f - w0 - w1;
        float x0 = vb[3*i0+0], y0 = vb[3*i0+1], z0 = vb[3*i0+2];
        float x1 = vb[3*i1+0], y1 = vb[3*i1+1], z1 = vb[3*i1+2];
        float x2 = vb[3*i2+0], y2 = vb[3*i2+1], z2 = vb[3*i2+2];
        float x = w0 * x0 + w1 * x1 + w2 * x2;
        float y = w0 * y0 + w1 * y1 + w2 * y2;
        float z = w0 * z0 + w1 * z1 + w2 * z2;
        float vol = spart[p];
        float pw  = (y < 0.f) ? fmaf(-100.f, y, 1.f) : __expf(-10.f * y);
        sVx += x * vol;  sVz += z * vol;
        sPx += x * pw;   sPz += z * pw;   sPw += pw;
    }

    float vals[5] = {sVx, sVz, sPx, sPz, sPw};
    #pragma unroll
    for (int q = 0; q < 5; q++) {
        float s = vals[q];
        #pragma unroll
        for (int off = 32; off > 0; off >>= 1) s += __shfl_down(s, off, 64);
        vals[q] = s;
    }
    float* sred5 = &sredp[0][0];   // reuse (dead after spart): 16*5*4 = 320 B
    if (lane == 0) {
        #pragma unroll
        for (int q = 0; q < 5; q++) sred5[wave * 5 + q] = vals[q];
    }
    __syncthreads();
    if (tid == 0) {
        float r[5];
        #pragma unroll
        for (int q = 0; q < 5; q++) {
            float s = 0.f;
            #pragma unroll
            for (int w = 0; w < NWAVES; w++) s += sred5[w * 5 + q];
            r[q] = s;
        }
        float sVol = 0.f;
        #pragma unroll
        for (int q = 0; q < NPARTS; q++) sVol += spart[q] * (float)counts[2 + q];
        float invVol = 1.0f / sVol;
        float invPw  = 1.0f / (r[4] + 1e-6f);
        float comx = r[0] * invVol, comz = r[1] * invVol;
        float copx = r[2] * invPw,  copz = r[3] * invPw;
        float d0 = comx - copx, d2 = comz - copz;
        out[b] = sqrtf(d0 * d0 + d2 * d2);
    }
}

extern "C" void kernel_launch(void* const* d_in, const int* in_sizes, int n_in,
                              void* d_out, int out_size, void* d_ws, size_t ws_size,
                              hipStream_t stream) {
    const float* vertices = (const float*)d_in[0];
    const float* bary     = (const float*)d_in[1];
    const int*   faces    = (const int*)d_in[2];
    const int*   hd_fid   = (const int*)d_in[3];
    const int*   part_fid = (const int*)d_in[4];
    float* out = (float*)d_out;

    // ws layout (16B-aligned): f_pack | hd_pack | ovf_h | ovf_f | counts
    char* ws = (char*)d_ws;
    uint2* f_pack  = (uint2*)ws;                          // 110208
    uint4* hd_pack = (uint4*)(ws + 110208);               // 320000
    uint4* ovf_h   = (uint4*)(ws + 110208 + 320000);      // 320000 (worst case)
    uint2* ovf_f   = (uint2*)(ws + 110208 + 640000);      // 110208 (worst case)
    int*   counts  = (int*)(ws + 110208 + 640000 + 110208);

    prep<<<2, 1024, 0, stream>>>(bary, faces, hd_fid, part_fid,
                                 f_pack, hd_pack, ovf_f, ovf_h, counts);
    stab_kernel<<<NB, NTHREADS, 0, stream>>>(vertices, f_pack, hd_pack, ovf_f, ovf_h, counts, out);
}

// Round 12
// 54.829 us; speedup vs baseline: 1.9731x; 1.9731x over previous
//
#include <hip/hip_runtime.h>
#include <math.h>

#define NB     512
#define NV     6890
#define NF     13776
#define NVHD   20000
#define NPARTS 10
#define NTHREADS 1024
#define NWAVES (NTHREADS/64)
#define CUT    6697                // verts < CUT live in LDS
#define NCHF   ((NF + 63) / 64)    // 216 wave-chunks (faces)
#define NCHH   ((NVHD + 63) / 64)  // 313 wave-chunks (HD)
#define FBLK   ((NF + 255) / 256)  // 54 (54*4 == NCHF exactly)
#define HBLK   ((NVHD + 255) / 256)// 79

// ---- K1: per-wave-chunk key counts (wide, deterministic) ----
// faces: key = bad?10:part (11 keys). HD: key = bad?1:0 (2 keys).
__global__ __launch_bounds__(256) void count_kernel(
    const int* __restrict__ faces, const int* __restrict__ part_fid,
    const int* __restrict__ hd_fid,
    int* __restrict__ cntF,   // [11][NCHF]
    int* __restrict__ cntH)   // [2][NCHH]
{
    const int wv = threadIdx.x >> 6, lane = threadIdx.x & 63;
    if (blockIdx.x < FBLK) {
        int c = blockIdx.x * 4 + wv;            // < NCHF by construction
        int i = c * 64 + lane;
        int key = -1;
        if (i < NF) {
            int i0 = faces[3*i+0], i1 = faces[3*i+1], i2 = faces[3*i+2];
            bool bad = (i0 >= CUT) || (i1 >= CUT) || (i2 >= CUT);
            key = bad ? 10 : part_fid[i];
        }
        #pragma unroll
        for (int q = 0; q < 11; q++) {
            unsigned long long m = __ballot(key == q);
            if (lane == 0) cntF[q * NCHF + c] = (int)__popcll(m);
        }
    } else {
        int c = (blockIdx.x - FBLK) * 4 + wv;
        if (c < NCHH) {
            int i = c * 64 + lane;
            int key = -1;
            if (i < NVHD) {
                int fid = hd_fid[i];
                int i0 = faces[3*fid+0], i1 = faces[3*fid+1], i2 = faces[3*fid+2];
                key = ((i0 >= CUT) || (i1 >= CUT) || (i2 >= CUT)) ? 1 : 0;
            }
            #pragma unroll
            for (int q = 0; q < 2; q++) {
                unsigned long long m = __ballot(key == q);
                if (lane == 0) cntH[q * NCHH + c] = (int)__popcll(m);
            }
        }
    }
}

// ---- K2: tiny scan (1 block): per-row exclusive chunk offsets + key bases ----
// offs[0..11] = face key starts (offs[11]=NF); offs[12..14] = HD {0, nClean, NVHD}
__global__ __launch_bounds__(1024) void scan_kernel(
    int* __restrict__ cntF, int* __restrict__ cntH, int* __restrict__ offs)
{
    __shared__ int rowtot[13];
    const int wv = threadIdx.x >> 6, lane = threadIdx.x & 63;
    if (wv < 11) {
        int* row = cntF + wv * NCHF;
        int carry = 0;
        #pragma unroll
        for (int seg = 0; seg < (NCHF + 63) / 64; seg++) {
            int idx = seg * 64 + lane;
            int v = (idx < NCHF) ? row[idx] : 0;
            int incl = v;
            #pragma unroll
            for (int off = 1; off < 64; off <<= 1) { int n = __shfl_up(incl, off, 64); if (lane >= off) incl += n; }
            if (idx < NCHF) row[idx] = incl - v + carry;
            carry += __shfl(incl, 63, 64);
        }
        if (lane == 0) rowtot[wv] = carry;
    } else if (wv < 13) {
        int r = wv - 11;
        int* row = cntH + r * NCHH;
        int carry = 0;
        #pragma unroll
        for (int seg = 0; seg < (NCHH + 63) / 64; seg++) {
            int idx = seg * 64 + lane;
            int v = (idx < NCHH) ? row[idx] : 0;
            int incl = v;
            #pragma unroll
            for (int off = 1; off < 64; off <<= 1) { int n = __shfl_up(incl, off, 64); if (lane >= off) incl += n; }
            if (idx < NCHH) row[idx] = incl - v + carry;
            carry += __shfl(incl, 63, 64);
        }
        if (lane == 0) rowtot[11 + r] = carry;
    }
    __syncthreads();
    if (threadIdx.x == 0) {
        int r = 0;
        #pragma unroll
        for (int q = 0; q < 11; q++) { offs[q] = r; r += rowtot[q]; }
        offs[11] = r;                              // == NF
        offs[12] = 0;
        offs[13] = rowtot[11];                     // nCleanH
        offs[14] = rowtot[11] + rowtot[12];        // == NVHD
    }
}

// ---- K3: wide deterministic scatter into sorted tables ----
__global__ __launch_bounds__(256) void scatter_kernel(
    const float* __restrict__ bary, const int* __restrict__ faces,
    const int* __restrict__ hd_fid, const int* __restrict__ part_fid,
    const int* __restrict__ cntF, const int* __restrict__ cntH,
    const int* __restrict__ offs,
    uint2* __restrict__ f_sorted, uint4* __restrict__ hd_sorted)
{
    const int wv = threadIdx.x >> 6, lane = threadIdx.x & 63;
    const unsigned long long low = (1ull << lane) - 1ull;
    if (blockIdx.x < FBLK) {
        int c = blockIdx.x * 4 + wv;
        int i = c * 64 + lane;
        int key = -1; uint2 ft = make_uint2(0u, 0u);
        if (i < NF) {
            int i0 = faces[3*i+0], i1 = faces[3*i+1], i2 = faces[3*i+2];
            int p  = part_fid[i];
            bool bad = (i0 >= CUT) || (i1 >= CUT) || (i2 >= CUT);
            key = bad ? 10 : p;
            ft = make_uint2((unsigned)i0 | ((unsigned)i1 << 16),
                            (unsigned)i2 | ((unsigned)p  << 16));
        }
        #pragma unroll
        for (int q = 0; q < 11; q++) {
            unsigned long long m = __ballot(key == q);
            if (key == q) {
                int rank = (int)__popcll(m & low);
                f_sorted[offs[q] + cntF[q * NCHF + c] + rank] = ft;
            }
        }
    } else {
        int c = (blockIdx.x - FBLK) * 4 + wv;
        if (c < NCHH) {
            int i = c * 64 + lane;
            int key = -1; uint4 hp = make_uint4(0u, 0u, 0u, 0u);
            if (i < NVHD) {
                int fid = hd_fid[i];
                int i0 = faces[3*fid+0], i1 = faces[3*fid+1], i2 = faces[3*fid+2];
                float b0 = bary[3*i+0], b1 = bary[3*i+1], b2 = bary[3*i+2];
                float inv = 1.0f / (b0 + b1 + b2);
                hp = make_uint4((unsigned)i0 | ((unsigned)i1 << 16),
                                (unsigned)i2 | ((unsigned)part_fid[fid] << 16),
                                __float_as_uint(b0*inv), __float_as_uint(b1*inv));
                key = ((i0 >= CUT) || (i1 >= CUT) || (i2 >= CUT)) ? 1 : 0;
            }
            #pragma unroll
            for (int q = 0; q < 2; q++) {
                unsigned long long m = __ballot(key == q);
                if (key == q) {
                    int rank = (int)__popcll(m & low);
                    hd_sorted[offs[12 + q] + cntH[q * NCHH + c] + rank] = hp;
                }
            }
        }
    }
}

__global__ __launch_bounds__(NTHREADS, 8) void stab_kernel(
    const float* __restrict__ vertices,    // [B][V][3] f32
    const uint2* __restrict__ f_sorted,    // [NF] keys 0..9 clean-by-part, 10 bad
    const uint4* __restrict__ hd_sorted,   // [NVHD] clean prefix, bad suffix
    const int*   __restrict__ offs,
    float*       __restrict__ out)         // [B]
{
    __shared__ float2 sxy[CUT];              // 53576 B
    __shared__ float  szz[CUT];              // 26788 B
    __shared__ float  spart[NPARTS];         // 40 B
    __shared__ float  sredp[NWAVES][NPARTS]; // 640 B  -> total 81044 (2 blocks/CU)

    const int tid  = threadIdx.x;
    const int b    = blockIdx.x;
    const int wave = tid >> 6;
    const int lane = tid & 63;
    const float* __restrict__ vb = vertices + (size_t)b * (NV * 3);

    int offF[12];
    #pragma unroll
    for (int q = 0; q < 12; q++) offF[q] = offs[q];
    const int hClean = offs[13];

    // ---- Phase A: stage verts [0,CUT) ----
    for (int v = tid; v < CUT; v += NTHREADS) {
        float x = vb[3 * v + 0];
        float y = vb[3 * v + 1];
        float z = vb[3 * v + 2];
        sxy[v] = make_float2(x, y);
        szz[v] = z;
    }
    __syncthreads();

    // ---- Phase B: 10 static per-part sub-loops, binning-free ----
    float accp[NPARTS];
    #pragma unroll
    for (int q = 0; q < NPARTS; q++) accp[q] = 0.f;

    #pragma unroll
    for (int p = 0; p < NPARTS; p++) {
        float va = 0.f;
        for (int f = offF[p] + tid; f < offF[p + 1]; f += NTHREADS) {
            uint2 ft = f_sorted[f];
            int i0 = ft.x & 0xFFFF, i1 = ft.x >> 16, i2 = ft.y & 0xFFFF;
            float2 t0 = sxy[i0]; float z0 = szz[i0];
            float2 t1 = sxy[i1]; float z1 = szz[i1];
            float2 t2 = sxy[i2]; float z2 = szz[i2];
            float cx = t0.y * z1   - z0   * t1.y;
            float cy = z0   * t1.x - t0.x * z1;
            float cz = t0.x * t1.y - t0.y * t1.x;
            va += (cx * t2.x + cy * t2.y + cz * z2) * (1.0f / 6.0f);
        }
        accp[p] += va;
    }
    // bad faces (rare): global gathers, runtime binning
    for (int f = offF[10] + tid; f < NF; f += NTHREADS) {
        uint2 ft = f_sorted[f];
        int i0 = ft.x & 0xFFFF, i1 = ft.x >> 16;
        int i2 = ft.y & 0xFFFF, p  = (int)(ft.y >> 16);
        float x0 = vb[3*i0+0], y0 = vb[3*i0+1], z0 = vb[3*i0+2];
        float x1 = vb[3*i1+0], y1 = vb[3*i1+1], z1 = vb[3*i1+2];
        float x2 = vb[3*i2+0], y2 = vb[3*i2+1], z2 = vb[3*i2+2];
        float cx = y0 * z1 - z0 * y1;
        float cy = z0 * x1 - x0 * z1;
        float cz = x0 * y1 - y0 * x1;
        float vol = (cx * x2 + cy * y2 + cz * z2) * (1.0f / 6.0f);
        #pragma unroll
        for (int q = 0; q < NPARTS; q++) accp[q] += (p == q) ? vol : 0.f;
    }

    #pragma unroll
    for (int q = 0; q < NPARTS; q++) {
        float s = accp[q];
        #pragma unroll
        for (int off = 32; off > 0; off >>= 1) s += __shfl_down(s, off, 64);
        accp[q] = s;
    }
    if (lane == 0) {
        #pragma unroll
        for (int q = 0; q < NPARTS; q++) sredp[wave][q] = accp[q];
    }
    __syncthreads();
    if (tid < NPARTS) {
        float s = 0.f;
        #pragma unroll
        for (int w = 0; w < NWAVES; w++) s += sredp[w][tid];
        spart[tid] = s;
    }
    __syncthreads();

    // ---- Phase C: clean HD prefix (pure LDS, branch-free) ----
    float sVx = 0.f, sVz = 0.f, sVol = 0.f;
    float sPx = 0.f, sPz = 0.f, sPw = 0.f;

    #pragma unroll 2
    for (int v = tid; v < hClean; v += NTHREADS) {
        uint4 hp = hd_sorted[v];
        int i0 = hp.x & 0xFFFF, i1 = hp.x >> 16;
        int i2 = hp.y & 0xFFFF, p  = (int)(hp.y >> 16);
        float w0 = __uint_as_float(hp.z);
        float w1 = __uint_as_float(hp.w);
        float w2 = 1.0f - w0 - w1;
        float2 t0 = sxy[i0]; float z0 = szz[i0];
        float2 t1 = sxy[i1]; float z1 = szz[i1];
        float2 t2 = sxy[i2]; float z2 = szz[i2];
        float x = w0 * t0.x + w1 * t1.x + w2 * t2.x;
        float y = w0 * t0.y + w1 * t1.y + w2 * t2.y;
        float z = w0 * z0   + w1 * z1   + w2 * z2;
        float vol = spart[p];
        float pw  = (y < 0.f) ? fmaf(-100.f, y, 1.f) : __expf(-10.f * y);
        sVx += x * vol;  sVz += z * vol;  sVol += vol;
        sPx += x * pw;   sPz += z * pw;   sPw += pw;
    }
    // bad HD suffix (rare): global gathers
    for (int v = hClean + tid; v < NVHD; v += NTHREADS) {
        uint4 hp = hd_sorted[v];
        int i0 = hp.x & 0xFFFF, i1 = hp.x >> 16;
        int i2 = hp.y & 0xFFFF, p  = (int)(hp.y >> 16);
        float w0 = __uint_as_float(hp.z);
        float w1 = __uint_as_float(hp.w);
        float w2 = 1.0f - w0 - w1;
        float x0 = vb[3*i0+0], y0 = vb[3*i0+1], z0 = vb[3*i0+2];
        float x1 = vb[3*i1+0], y1 = vb[3*i1+1], z1 = vb[3*i1+2];
        float x2 = vb[3*i2+0], y2 = vb[3*i2+1], z2 = vb[3*i2+2];
        float x = w0 * x0 + w1 * x1 + w2 * x2;
        float y = w0 * y0 + w1 * y1 + w2 * y2;
        float z = w0 * z0 + w1 * z1 + w2 * z2;
        float vol = spart[p];
        float pw  = (y < 0.f) ? fmaf(-100.f, y, 1.f) : __expf(-10.f * y);
        sVx += x * vol;  sVz += z * vol;  sVol += vol;
        sPx += x * pw;   sPz += z * pw;   sPw += pw;
    }

    float vals[6] = {sVx, sVz, sVol, sPx, sPz, sPw};
    #pragma unroll
    for (int q = 0; q < 6; q++) {
        float s = vals[q];
        #pragma unroll
        for (int off = 32; off > 0; off >>= 1) s += __shfl_down(s, off, 64);
        vals[q] = s;
    }
    float* sred6 = &sredp[0][0];   // reuse (dead after spart): 16*6*4 = 384 B
    if (lane == 0) {
        #pragma unroll
        for (int q = 0; q < 6; q++) sred6[wave * 6 + q] = vals[q];
    }
    __syncthreads();
    if (tid == 0) {
        float r[6];
        #pragma unroll
        for (int q = 0; q < 6; q++) {
            float s = 0.f;
            #pragma unroll
            for (int w = 0; w < NWAVES; w++) s += sred6[w * 6 + q];
            r[q] = s;
        }
        float invVol = 1.0f / r[2];
        float invPw  = 1.0f / (r[5] + 1e-6f);
        float comx = r[0] * invVol, comz = r[1] * invVol;
        float copx = r[3] * invPw,  copz = r[4] * invPw;
        float d0 = comx - copx, d2 = comz - copz;
        out[b] = sqrtf(d0 * d0 + d2 * d2);
    }
}

extern "C" void kernel_launch(void* const* d_in, const int* in_sizes, int n_in,
                              void* d_out, int out_size, void* d_ws, size_t ws_size,
                              hipStream_t stream) {
    const float* vertices = (const float*)d_in[0];
    const float* bary     = (const float*)d_in[1];
    const int*   faces    = (const int*)d_in[2];
    const int*   hd_fid   = (const int*)d_in[3];
    const int*   part_fid = (const int*)d_in[4];
    float* out = (float*)d_out;

    // ws layout: hd_sorted(16B) | f_sorted | cntF | cntH | offs
    char* ws = (char*)d_ws;
    uint4* hd_sorted = (uint4*)ws;                               // 320000
    uint2* f_sorted  = (uint2*)(ws + 320000);                    // 110208
    int*   cntF      = (int*)(ws + 320000 + 110208);             // 11*216*4 = 9504
    int*   cntH      = (int*)(ws + 320000 + 110208 + 9504);      // 2*313*4 = 2504
    int*   offs      = (int*)(ws + 320000 + 110208 + 9504 + 2504); // 15*4

    count_kernel<<<FBLK + HBLK, 256, 0, stream>>>(faces, part_fid, hd_fid, cntF, cntH);
    scan_kernel<<<1, 1024, 0, stream>>>(cntF, cntH, offs);
    scatter_kernel<<<FBLK + HBLK, 256, 0, stream>>>(bary, faces, hd_fid, part_fid,
                                                    cntF, cntH, offs, f_sorted, hd_sorted);
    stab_kernel<<<NB, NTHREADS, 0, stream>>>(vertices, f_sorted, hd_sorted, offs, out);
}